// Round 3
// baseline (464.117 us; speedup 1.0000x reference)
//
#include <hip/hip_runtime.h>
#include <math.h>

#define CC 4
#define HH 64
#define WW 64
#define NN (HH*WW)
#define NTH 256
#define GRP 4            // 4-pixel groups per thread (4 groups x 4 px = 16 px/thread)
#define LDW 65           // padded LDS row stride (bank-conflict-free windows)

#if __has_builtin(__builtin_amdgcn_exp2f)
#define FEXP2(x) __builtin_amdgcn_exp2f(x)
#else
#define FEXP2(x) exp2f(x)
#endif
#if __has_builtin(__builtin_amdgcn_logf)
#define FLOG2(x) __builtin_amdgcn_logf(x)   // v_log_f32 = log2
#else
#define FLOG2(x) log2f(x)
#endif
#define LOG2E 1.4426950408889634f

__device__ __forceinline__ float softplusf(float x) {
    return (x > 20.f) ? x : log1pf(expf(x));
}
__device__ __forceinline__ float sigmoidf(float x) {
    return 1.f / (1.f + expf(-x));
}

// one-barrier block reduce; each call must use a distinct scratch slot sc[4]
__device__ __forceinline__ float bred(float v, float* sc, bool do_max) {
#pragma unroll
    for (int o = 32; o > 0; o >>= 1) {
        float other = __shfl_down(v, o, 64);
        v = do_max ? fmaxf(v, other) : (v + other);
    }
    if ((threadIdx.x & 63) == 0) sc[threadIdx.x >> 6] = v;
    __syncthreads();
    return do_max ? fmaxf(fmaxf(sc[0], sc[1]), fmaxf(sc[2], sc[3]))
                  : ((sc[0] + sc[1]) + (sc[2] + sc[3]));
}

__global__ __launch_bounds__(NTH, 5)
void slam_kernel(const float* __restrict__ map_state,
                 const float* __restrict__ weight_state,
                 const float* __restrict__ key,
                 const float* __restrict__ beta,
                 const float* __restrict__ gate,
                 const float* __restrict__ shift,
                 const float* __restrict__ sharpen,
                 const float* __restrict__ add_patch_logits,
                 const float* __restrict__ erase_patch_logits,
                 float* __restrict__ out_map,
                 float* __restrict__ out_w,
                 float* __restrict__ out_rv)
{
    __shared__ float sw[HH * LDW];      // 16.6 KB, the single weight-field buffer
    __shared__ float spatch[2 * CC * 9];
    __shared__ float sred[8][4];

    const int b = blockIdx.x;
    const int tid = threadIdx.x;

    // ---- per-batch scalars ----
    const float* keyb = key + b * CC;
    float k0 = keyb[0], k1 = keyb[1], k2 = keyb[2], k3 = keyb[3];
    {
        float inv = rsqrtf(fmaxf(k0*k0 + k1*k1 + k2*k2 + k3*k3, 1e-24f));
        k0 *= inv; k1 *= inv; k2 *= inv; k3 *= inv;
    }
    const float beta_pos  = softplusf(beta[b]) + 1e-6f;
    const float g         = sigmoidf(gate[b]);
    const float sharp_pos = 1.f + softplusf(sharpen[b]);

    // shift-kernel softmax (9 vals, registers, per-thread redundant)
    float sk[9];
    {
        const float* sh = shift + b * 9;
        float m = sh[0];
#pragma unroll
        for (int i = 1; i < 9; ++i) m = fmaxf(m, sh[i]);
        float s = 0.f;
#pragma unroll
        for (int i = 0; i < 9; ++i) { sk[i] = FEXP2((sh[i] - m) * LOG2E); s += sk[i]; }
        float inv = 1.f / s;
#pragma unroll
        for (int i = 0; i < 9; ++i) sk[i] *= inv;
    }

    // patch sigmoids into LDS
    if (tid < 2 * CC * 9) {
        float v = (tid < CC * 9) ? add_patch_logits[b * CC * 9 + tid]
                                 : erase_patch_logits[b * CC * 9 + (tid - CC * 9)];
        spatch[tid] = sigmoidf(v);
    }

    const float*  mapb = map_state    + (size_t)b * CC * NN;
    const float4* mp4  = (const float4*)mapb;
    const float4* pw4  = (const float4*)(weight_state + (size_t)b * NN);
    float4*       om4  = (float4*)(out_map + (size_t)b * CC * NN);
    float4*       ow4  = (float4*)(out_w   + (size_t)b * NN);

    float z[16];   // per-thread staging: logits -> exp -> conv result

    // ---- Phase 1: similarity logits (registers only) ----
    float lmax = -INFINITY;
#pragma unroll
    for (int gix = 0; gix < GRP; ++gix) {
        const int base = tid + gix * NTH;       // float4 index; pixel P = 4*base
        float4 mv[CC];
#pragma unroll
        for (int ch = 0; ch < CC; ++ch) mv[ch] = mp4[ch * (NN/4) + base];
#pragma unroll
        for (int j = 0; j < 4; ++j) {
            float a0 = ((const float*)&mv[0])[j];
            float a1 = ((const float*)&mv[1])[j];
            float a2 = ((const float*)&mv[2])[j];
            float a3 = ((const float*)&mv[3])[j];
            float inv = rsqrtf(fmaxf(a0*a0 + a1*a1 + a2*a2 + a3*a3, 1e-24f));
            float zz = beta_pos * (a0*k0 + a1*k1 + a2*k2 + a3*k3) * inv;
            z[gix*4 + j] = zz;
            lmax = fmaxf(lmax, zz);
        }
    }
    const float zmax = bred(lmax, sred[0], true);

    float lsum = 0.f;
#pragma unroll
    for (int i = 0; i < 16; ++i) {
        float e = FEXP2((z[i] - zmax) * LOG2E);
        z[i] = e;
        lsum += e;
    }
    const float Z = bred(lsum, sred[1], false);
    const float gZinv = g / Z;
    const float g1 = 1.f - g;

    // gate-blend and stage gated weights into LDS
#pragma unroll
    for (int gix = 0; gix < GRP; ++gix) {
        const int base = tid + gix * NTH;
        const int P = 4 * base, h = P >> 6, w0 = P & 63;
        float4 pw = pw4[base];
        float* row = sw + h * LDW + w0;
#pragma unroll
        for (int j = 0; j < 4; ++j)
            row[j] = gZinv * z[gix*4 + j] + g1 * ((const float*)&pw)[j];
    }
    __syncthreads();

    // ---- Phase 2: circular 3x3 conv + sharpen (results in regs) ----
    float lsum1 = 0.f;
#pragma unroll
    for (int gix = 0; gix < GRP; ++gix) {
        const int P = 4 * (tid + gix * NTH), h = P >> 6, w0 = P & 63;
        const int rows[3] = { (h + 1) & 63, h, (h + 63) & 63 };  // dh=0,1,2
        const int cm = (w0 + 63) & 63, cp = (w0 + 4) & 63;
        float buf[3][6];
#pragma unroll
        for (int dh = 0; dh < 3; ++dh) {
            const float* rp = sw + rows[dh] * LDW;
            buf[dh][0] = rp[cm];
            buf[dh][1] = rp[w0];
            buf[dh][2] = rp[w0 + 1];
            buf[dh][3] = rp[w0 + 2];
            buf[dh][4] = rp[w0 + 3];
            buf[dh][5] = rp[cp];
        }
#pragma unroll
        for (int j = 0; j < 4; ++j) {
            float acc = 0.f;
#pragma unroll
            for (int dh = 0; dh < 3; ++dh)
                acc += sk[dh*3+0]*buf[dh][j+2] + sk[dh*3+1]*buf[dh][j+1] + sk[dh*3+2]*buf[dh][j];
            float p = FEXP2(sharp_pos * FLOG2(fmaxf(acc, 1e-6f)));
            z[gix*4 + j] = p;
            lsum1 += p;
        }
    }
    const float S1 = bred(lsum1, sred[2], false);   // barrier: conv reads done
    const float inv1 = 1.f / (S1 + 1e-6f);
    const float S2 = S1 * inv1;                      // == sum of first-normalized weights
    const float scale = inv1 / (S2 + 1e-6f);

    // final weights -> LDS + global
#pragma unroll
    for (int gix = 0; gix < GRP; ++gix) {
        const int base = tid + gix * NTH;
        const int P = 4 * base, h = P >> 6, w0 = P & 63;
        float* row = sw + h * LDW + w0;
        float4 o;
#pragma unroll
        for (int j = 0; j < 4; ++j) {
            float wv = z[gix*4 + j] * scale;
            row[j] = wv;
            ((float*)&o)[j] = wv;
        }
        ow4[base] = o;
    }
    __syncthreads();

    // ---- Phase 3: patch apply (zero-pad), map update, read vector ----
    float rv[CC] = {0.f, 0.f, 0.f, 0.f};
#pragma unroll
    for (int cp2 = 0; cp2 < 2; ++cp2) {               // 2-channel blocking
        float pa[2][9], pe[2][9];
#pragma unroll
        for (int c = 0; c < 2; ++c) {
            const int ch = cp2 * 2 + c;
#pragma unroll
            for (int t = 0; t < 9; ++t) {
                pa[c][t] = spatch[ch * 9 + t];
                pe[c][t] = spatch[CC * 9 + ch * 9 + t];
            }
        }
#pragma unroll
        for (int gix = 0; gix < GRP; ++gix) {
            const int base = tid + gix * NTH;
            const int P = 4 * base, h = P >> 6, w0 = P & 63;
            float buf[3][6];
#pragma unroll
            for (int dh = 0; dh < 3; ++dh) {
                const int r = h + 1 - dh;
                if ((unsigned)r < (unsigned)HH) {
                    const float* rp = sw + r * LDW;
                    buf[dh][0] = (w0 > 0) ? rp[w0 - 1] : 0.f;
                    buf[dh][1] = rp[w0];
                    buf[dh][2] = rp[w0 + 1];
                    buf[dh][3] = rp[w0 + 2];
                    buf[dh][4] = rp[w0 + 3];
                    buf[dh][5] = (w0 + 4 < WW) ? rp[w0 + 4] : 0.f;
                } else {
#pragma unroll
                    for (int k = 0; k < 6; ++k) buf[dh][k] = 0.f;
                }
            }
            const float wn[4] = { buf[1][1], buf[1][2], buf[1][3], buf[1][4] };
#pragma unroll
            for (int c = 0; c < 2; ++c) {
                const int ch = cp2 * 2 + c;
                float4 m4 = mp4[ch * (NN/4) + base];
                float4 o;
#pragma unroll
                for (int j = 0; j < 4; ++j) {
                    float a = 0.f, e = 0.f;
#pragma unroll
                    for (int dh = 0; dh < 3; ++dh) {
                        a += pa[c][dh*3+0]*buf[dh][j+2] + pa[c][dh*3+1]*buf[dh][j+1] + pa[c][dh*3+2]*buf[dh][j];
                        e += pe[c][dh*3+0]*buf[dh][j+2] + pe[c][dh*3+1]*buf[dh][j+1] + pe[c][dh*3+2]*buf[dh][j];
                    }
                    e = fminf(fmaxf(e, 0.f), 1.f);
                    float mu = ((const float*)&m4)[j] * (1.f - e) + a;
                    ((float*)&o)[j] = mu;
                    rv[ch] += mu * wn[j];
                }
                om4[ch * (NN/4) + base] = o;
            }
        }
    }

    // read-vector block reduction (4 channels)
#pragma unroll
    for (int c = 0; c < CC; ++c) {
        float v = rv[c];
#pragma unroll
        for (int o = 32; o > 0; o >>= 1) v += __shfl_down(v, o, 64);
        if ((tid & 63) == 0) sred[4 + c][tid >> 6] = v;
    }
    __syncthreads();
    if (tid == 0) {
#pragma unroll
        for (int c = 0; c < CC; ++c)
            out_rv[(size_t)b * CC + c] =
                (sred[4+c][0] + sred[4+c][1]) + (sred[4+c][2] + sred[4+c][3]);
    }
}

extern "C" void kernel_launch(void* const* d_in, const int* in_sizes, int n_in,
                              void* d_out, int out_size, void* d_ws, size_t ws_size,
                              hipStream_t stream) {
    const float* map_state          = (const float*)d_in[0];
    const float* weight_state       = (const float*)d_in[1];
    const float* key                = (const float*)d_in[2];
    const float* beta               = (const float*)d_in[3];
    const float* gate               = (const float*)d_in[4];
    const float* shift              = (const float*)d_in[5];
    const float* sharpen            = (const float*)d_in[6];
    // d_in[7] = erase, d_in[8] = add : unused by the reference
    const float* add_patch_logits   = (const float*)d_in[9];
    const float* erase_patch_logits = (const float*)d_in[10];

    const int B = in_sizes[1] / NN;   // weight_state is (B, H*W)

    float* out_map = (float*)d_out;
    float* out_w   = out_map + (size_t)B * CC * NN;
    float* out_rv  = out_w   + (size_t)B * NN;

    slam_kernel<<<B, NTH, 0, stream>>>(map_state, weight_state, key, beta, gate,
                                       shift, sharpen, add_patch_logits,
                                       erase_patch_logits, out_map, out_w, out_rv);
}

// Round 4
// 86.975 us; speedup vs baseline: 5.3362x; 5.3362x over previous
//
#include <hip/hip_runtime.h>
#include <math.h>

#define CC 4
#define HH 64
#define WW 64
#define NN (HH*WW)
#define NTH 256
#define GRP 4            // 4 float4-groups per thread = 16 pixels/thread
#define LDW 65           // padded LDS row stride: scalar window reads are 2-way (free)

#if __has_builtin(__builtin_amdgcn_exp2f)
#define FEXP2(x) __builtin_amdgcn_exp2f(x)
#else
#define FEXP2(x) exp2f(x)
#endif
#if __has_builtin(__builtin_amdgcn_logf)
#define FLOG2(x) __builtin_amdgcn_logf(x)   // v_log_f32 = log2
#else
#define FLOG2(x) log2f(x)
#endif
#define LOG2E 1.4426950408889634f

__device__ __forceinline__ float softplusf(float x) {
    return (x > 20.f) ? x : log1pf(expf(x));
}
__device__ __forceinline__ float sigmoidf(float x) {
    return 1.f / (1.f + expf(-x));
}

// one-barrier block reduce; each call must use a DISTINCT scratch slot sc[4]
__device__ __forceinline__ float bred(float v, float* sc, bool do_max) {
#pragma unroll
    for (int o = 32; o > 0; o >>= 1) {
        float other = __shfl_down(v, o, 64);
        v = do_max ? fmaxf(v, other) : (v + other);
    }
    if ((threadIdx.x & 63) == 0) sc[threadIdx.x >> 6] = v;
    __syncthreads();
    return do_max ? fmaxf(fmaxf(sc[0], sc[1]), fmaxf(sc[2], sc[3]))
                  : ((sc[0] + sc[1]) + (sc[2] + sc[3]));
}

__global__ __launch_bounds__(NTH)
void slam_kernel(const float* __restrict__ map_state,
                 const float* __restrict__ weight_state,
                 const float* __restrict__ key,
                 const float* __restrict__ beta,
                 const float* __restrict__ gate,
                 const float* __restrict__ shift,
                 const float* __restrict__ sharpen,
                 const float* __restrict__ add_patch_logits,
                 const float* __restrict__ erase_patch_logits,
                 float* __restrict__ out_map,
                 float* __restrict__ out_w,
                 float* __restrict__ out_rv)
{
    __shared__ float sw[HH * LDW];      // 16.6 KB single weight-field buffer
    __shared__ float spatch[2 * CC * 9];
    __shared__ float sred[8][4];

    const int b = blockIdx.x;
    const int tid = threadIdx.x;

    // ---- per-batch scalars ----
    const float* keyb = key + b * CC;
    float k0 = keyb[0], k1 = keyb[1], k2 = keyb[2], k3 = keyb[3];
    {
        float inv = rsqrtf(fmaxf(k0*k0 + k1*k1 + k2*k2 + k3*k3, 1e-24f));
        k0 *= inv; k1 *= inv; k2 *= inv; k3 *= inv;
    }
    const float beta_pos  = softplusf(beta[b]) + 1e-6f;
    const float g         = sigmoidf(gate[b]);
    const float sharp_pos = 1.f + softplusf(sharpen[b]);

    // shift-kernel softmax (9 vals, registers)
    float sk[9];
    {
        const float* sh = shift + b * 9;
        float m = sh[0];
#pragma unroll
        for (int i = 1; i < 9; ++i) m = fmaxf(m, sh[i]);
        float s = 0.f;
#pragma unroll
        for (int i = 0; i < 9; ++i) { sk[i] = FEXP2((sh[i] - m) * LOG2E); s += sk[i]; }
        float inv = 1.f / s;
#pragma unroll
        for (int i = 0; i < 9; ++i) sk[i] *= inv;
    }

    // patch sigmoids into LDS
    if (tid < 2 * CC * 9) {
        float v = (tid < CC * 9) ? add_patch_logits[b * CC * 9 + tid]
                                 : erase_patch_logits[b * CC * 9 + (tid - CC * 9)];
        spatch[tid] = sigmoidf(v);
    }

    const float4* mp4 = (const float4*)(map_state    + (size_t)b * CC * NN);
    const float4* pw4 = (const float4*)(weight_state + (size_t)b * NN);
    float4*       om4 = (float4*)(out_map + (size_t)b * CC * NN);
    float4*       ow4 = (float4*)(out_w   + (size_t)b * NN);

    float z[16];   // per-thread staging: logits -> exp -> sharpened

    // ---- Phase 1: similarity logits (registers only) ----
    float lmax = -INFINITY;
#pragma unroll
    for (int gix = 0; gix < GRP; ++gix) {
        const int base = tid + gix * NTH;       // float4 index; pixel P = 4*base
        float4 mv0 = mp4[base];
        float4 mv1 = mp4[(NN/4) + base];
        float4 mv2 = mp4[2*(NN/4) + base];
        float4 mv3 = mp4[3*(NN/4) + base];
#pragma unroll
        for (int j = 0; j < 4; ++j) {
            float a0 = ((const float*)&mv0)[j];
            float a1 = ((const float*)&mv1)[j];
            float a2 = ((const float*)&mv2)[j];
            float a3 = ((const float*)&mv3)[j];
            float inv = rsqrtf(fmaxf(a0*a0 + a1*a1 + a2*a2 + a3*a3, 1e-24f));
            float zz = beta_pos * (a0*k0 + a1*k1 + a2*k2 + a3*k3) * inv;
            z[gix*4 + j] = zz;
            lmax = fmaxf(lmax, zz);
        }
    }
    const float zmax = bred(lmax, sred[0], true);

    float lsum = 0.f;
#pragma unroll
    for (int i = 0; i < 16; ++i) {
        float e = FEXP2((z[i] - zmax) * LOG2E);
        z[i] = e;
        lsum += e;
    }
    const float Z = bred(lsum, sred[1], false);
    const float gZinv = g / Z;
    const float g1 = 1.f - g;

    // gate-blend -> LDS
#pragma unroll
    for (int gix = 0; gix < GRP; ++gix) {
        const int base = tid + gix * NTH;
        const int P = 4 * base, h = P >> 6, w0 = P & 63;
        float4 pw = pw4[base];
        float* row = sw + h * LDW + w0;
#pragma unroll
        for (int j = 0; j < 4; ++j)
            row[j] = gZinv * z[gix*4 + j] + g1 * ((const float*)&pw)[j];
    }
    __syncthreads();

    // ---- Phase 2: circular 3x3 conv + sharpen (results in regs) ----
    float lsum1 = 0.f;
#pragma unroll
    for (int gix = 0; gix < GRP; ++gix) {
        const int P = 4 * (tid + gix * NTH), h = P >> 6, w0 = P & 63;
        const int r0 = (h + 1) & 63, r2 = (h + 63) & 63;   // dh=0, dh=2
        const int cm = (w0 + 63) & 63, cp = (w0 + 4) & 63;
        float buf[3][6];
        const int rr[3] = { r0, h, r2 };
#pragma unroll
        for (int dh = 0; dh < 3; ++dh) {
            const float* rp = sw + rr[dh] * LDW;
            buf[dh][0] = rp[cm];
            buf[dh][1] = rp[w0];
            buf[dh][2] = rp[w0 + 1];
            buf[dh][3] = rp[w0 + 2];
            buf[dh][4] = rp[w0 + 3];
            buf[dh][5] = rp[cp];
        }
#pragma unroll
        for (int j = 0; j < 4; ++j) {
            float acc = 0.f;
#pragma unroll
            for (int dh = 0; dh < 3; ++dh)
                acc += sk[dh*3+0]*buf[dh][j+2] + sk[dh*3+1]*buf[dh][j+1] + sk[dh*3+2]*buf[dh][j];
            float p = FEXP2(sharp_pos * FLOG2(fmaxf(acc, 1e-6f)));
            z[gix*4 + j] = p;
            lsum1 += p;
        }
    }
    const float S1 = bred(lsum1, sred[2], false);   // barrier: all conv reads done
    const float inv1 = 1.f / (S1 + 1e-6f);
    const float S2 = S1 * inv1;                     // sum of first-normalized weights
    const float scale = inv1 / (S2 + 1e-6f);

    // final weights -> LDS + global
#pragma unroll
    for (int gix = 0; gix < GRP; ++gix) {
        const int base = tid + gix * NTH;
        const int P = 4 * base, h = P >> 6, w0 = P & 63;
        float* row = sw + h * LDW + w0;
        float4 o;
#pragma unroll
        for (int j = 0; j < 4; ++j) {
            float wv = z[gix*4 + j] * scale;
            row[j] = wv;
            ((float*)&o)[j] = wv;
        }
        ow4[base] = o;
    }
    __syncthreads();

    // ---- Phase 3: patch apply (zero-pad), map update, read vector ----
    float rv[CC] = {0.f, 0.f, 0.f, 0.f};
#pragma unroll
    for (int gix = 0; gix < GRP; ++gix) {
        const int base = tid + gix * NTH;
        const int P = 4 * base, h = P >> 6, w0 = P & 63;
        float buf[3][6];
#pragma unroll
        for (int dh = 0; dh < 3; ++dh) {
            const int r = h + 1 - dh;
            if ((unsigned)r < (unsigned)HH) {
                const float* rp = sw + r * LDW;
                buf[dh][0] = (w0 > 0) ? rp[w0 - 1] : 0.f;
                buf[dh][1] = rp[w0];
                buf[dh][2] = rp[w0 + 1];
                buf[dh][3] = rp[w0 + 2];
                buf[dh][4] = rp[w0 + 3];
                buf[dh][5] = (w0 + 4 < WW) ? rp[w0 + 4] : 0.f;
            } else {
#pragma unroll
                for (int k = 0; k < 6; ++k) buf[dh][k] = 0.f;
            }
        }
        const float wn0 = buf[1][1], wn1 = buf[1][2], wn2 = buf[1][3], wn3 = buf[1][4];
#pragma unroll
        for (int ch = 0; ch < CC; ++ch) {
            const float* pa = spatch + ch * 9;            // LDS broadcast reads
            const float* pe = spatch + CC * 9 + ch * 9;
            float4 m4 = mp4[ch * (NN/4) + base];
            float4 o;
#pragma unroll
            for (int j = 0; j < 4; ++j) {
                float a = 0.f, e = 0.f;
#pragma unroll
                for (int dh = 0; dh < 3; ++dh) {
                    a += pa[dh*3+0]*buf[dh][j+2] + pa[dh*3+1]*buf[dh][j+1] + pa[dh*3+2]*buf[dh][j];
                    e += pe[dh*3+0]*buf[dh][j+2] + pe[dh*3+1]*buf[dh][j+1] + pe[dh*3+2]*buf[dh][j];
                }
                e = fminf(fmaxf(e, 0.f), 1.f);
                float mu = ((const float*)&m4)[j] * (1.f - e) + a;
                ((float*)&o)[j] = mu;
                float wn = (j == 0) ? wn0 : (j == 1) ? wn1 : (j == 2) ? wn2 : wn3;
                rv[ch] += mu * wn;
            }
            om4[ch * (NN/4) + base] = o;
        }
    }

    // read-vector block reduction (4 channels)
#pragma unroll
    for (int c = 0; c < CC; ++c) {
        float v = rv[c];
#pragma unroll
        for (int o = 32; o > 0; o >>= 1) v += __shfl_down(v, o, 64);
        if ((tid & 63) == 0) sred[4 + c][tid >> 6] = v;
    }
    __syncthreads();
    if (tid == 0) {
#pragma unroll
        for (int c = 0; c < CC; ++c)
            out_rv[(size_t)b * CC + c] =
                (sred[4+c][0] + sred[4+c][1]) + (sred[4+c][2] + sred[4+c][3]);
    }
}

extern "C" void kernel_launch(void* const* d_in, const int* in_sizes, int n_in,
                              void* d_out, int out_size, void* d_ws, size_t ws_size,
                              hipStream_t stream) {
    const float* map_state          = (const float*)d_in[0];
    const float* weight_state       = (const float*)d_in[1];
    const float* key                = (const float*)d_in[2];
    const float* beta               = (const float*)d_in[3];
    const float* gate               = (const float*)d_in[4];
    const float* shift              = (const float*)d_in[5];
    const float* sharpen            = (const float*)d_in[6];
    // d_in[7] = erase, d_in[8] = add : unused by the reference
    const float* add_patch_logits   = (const float*)d_in[9];
    const float* erase_patch_logits = (const float*)d_in[10];

    const int B = in_sizes[1] / NN;   // weight_state is (B, H*W)

    float* out_map = (float*)d_out;
    float* out_w   = out_map + (size_t)B * CC * NN;
    float* out_rv  = out_w   + (size_t)B * NN;

    slam_kernel<<<B, NTH, 0, stream>>>(map_state, weight_state, key, beta, gate,
                                       shift, sharpen, add_patch_logits,
                                       erase_patch_logits, out_map, out_w, out_rv);
}